// Round 1
// baseline (3548.601 us; speedup 1.0000x reference)
//
#include <hip/hip_runtime.h>
#include <math.h>

// Shapes:
// x:  [8, 2, 2048, 256]
// L1: conv k(8,1) s(4,1) p(2,0): -> [8,48,512,256]; gelu; 1x1 ->96; GLU -> [8,48,512,256]  (y1, ws)
// L2: conv: -> [8,96,128,256]; gelu (g2, staged in d_out latent region); 1x1 ->192; GLU -> [8,96,128,256] (beforvq, d_out)
// VQ: argmin over 1024 codes of ||f - c||^2, latent = codebook[idx]
//
// d_out layout (fp32): latent [25165824] | indices-as-float [262144] | beforvq [25165824]

#define H1IN 2048
#define H1OUT 512
#define H2IN 512
#define H2OUT 128
#define TT 256
#define NPTS 32768           // 128*256 per batch
#define LAT_ELEMS 25165824   // 8*96*128*256
#define IDX_ELEMS 262144

// ---------------- prep: transpose weights, codebook norms ----------------
__global__ __launch_bounds__(256) void prep_kernel(
    const float* __restrict__ w1, const float* __restrict__ w2,
    const float* __restrict__ w3, const float* __restrict__ w4,
    const float* __restrict__ cb,
    float* __restrict__ w1t, float* __restrict__ w2t,
    float* __restrict__ w3t, float* __restrict__ w4t,
    float* __restrict__ cnorm)
{
    int i = blockIdx.x * 256 + threadIdx.x;
    if (i < 768) {                       // w1t[(ci*8+kh)*48+oc] = w1[(oc*2+ci)*8+kh]
        int oc = i % 48; int r = i / 48;
        w1t[i] = w1[(oc * 2 + (r >> 3)) * 8 + (r & 7)];
    } else if (i < 5376) {               // w2t[c*96+oc] = w2[oc*48+c]
        int j = i - 768;
        int oc = j % 96, c = j / 96;
        w2t[j] = w2[oc * 48 + c];
    } else if (i < 42240) {              // w3t[(ci*8+kh)*96+oc] = w3[(oc*48+ci)*8+kh]
        int j = i - 5376;
        int oc = j % 96; int r = j / 96;
        w3t[j] = w3[(oc * 48 + (r >> 3)) * 8 + (r & 7)];
    } else if (i < 60672) {              // w4t[c*192+oc] = w4[oc*96+c]
        int j = i - 42240;
        int oc = j % 192, c = j / 192;
        w4t[j] = w4[oc * 96 + c];
    } else if (i < 61696) {              // cnorm[k] = sum_d cb[k][d]^2 (fp64 accumulate)
        int k = i - 60672;
        const float* cp = cb + (size_t)k * 96;
        double s = 0.0;
        for (int d = 0; d < 96; d++) s += (double)cp[d] * (double)cp[d];
        cnorm[k] = (float)s;
    }
}

__device__ __forceinline__ float gelu_tanh(float v) {
    float u = 0.7978845608028654f * (v + 0.044715f * v * v * v);
    return 0.5f * v * (1.f + tanhf(u));
}

// ---------------- layer 1 fused: conv + gelu + 1x1 + GLU ----------------
__global__ __launch_bounds__(256) void henc1_kernel(
    const float* __restrict__ x, const float* __restrict__ w1t,
    const float* __restrict__ b1, const float* __restrict__ w2t,
    const float* __restrict__ b2, float* __restrict__ y1)
{
    __shared__ float gs[48 * 256];
    int bh = blockIdx.x;           // b*512 + ho
    int ho = bh & 511, b = bh >> 9;
    int t = threadIdx.x;

    float g[48];
#pragma unroll
    for (int oc = 0; oc < 48; oc++) g[oc] = b1[oc];

    const float* xb = x + (size_t)b * 2 * H1IN * TT;
    int hbase = ho * 4 - 2;
    for (int ci = 0; ci < 2; ci++) {
        for (int kh = 0; kh < 8; kh++) {
            int hi = hbase + kh;
            float v = (hi >= 0 && hi < H1IN) ? xb[((size_t)ci * H1IN + hi) * TT + t] : 0.f;
            const float* wp = w1t + (ci * 8 + kh) * 48;
#pragma unroll
            for (int oc = 0; oc < 48; oc++) g[oc] = fmaf(v, wp[oc], g[oc]);
        }
    }
#pragma unroll
    for (int oc = 0; oc < 48; oc++) gs[oc * 256 + t] = gelu_tanh(g[oc]);

    float z[96];
#pragma unroll
    for (int oc = 0; oc < 96; oc++) z[oc] = b2[oc];
    for (int c = 0; c < 48; c++) {
        float v = gs[c * 256 + t];
        const float* wp = w2t + c * 96;
#pragma unroll
        for (int oc = 0; oc < 96; oc++) z[oc] = fmaf(v, wp[oc], z[oc]);
    }

    float* yb = y1 + (size_t)b * 48 * H1OUT * TT + (size_t)ho * TT + t;
#pragma unroll
    for (int co = 0; co < 48; co++) {
        float o = z[co] / (1.f + expf(-z[co + 48]));   // a * sigmoid(b)
        yb[(size_t)co * H1OUT * TT] = o;
    }
}

// ---------------- layer 2 conv + gelu ----------------
__global__ __launch_bounds__(256) void conv2a_kernel(
    const float* __restrict__ y1, const float* __restrict__ w3t,
    const float* __restrict__ b3, float* __restrict__ g2)
{
    int bh = blockIdx.x;           // b*128 + ho
    int ho = bh & 127, b = bh >> 7;
    int t = threadIdx.x;

    float g[96];
#pragma unroll
    for (int oc = 0; oc < 96; oc++) g[oc] = b3[oc];

    const float* xb = y1 + (size_t)b * 48 * H2IN * TT;
    int hbase = ho * 4 - 2;
    for (int kh = 0; kh < 8; kh++) {
        int hi = hbase + kh;
        if (hi < 0 || hi >= H2IN) continue;       // wave-uniform branch
        const float* xr = xb + (size_t)hi * TT + t;
        for (int ci = 0; ci < 48; ci++) {
            float v = xr[(size_t)ci * H2IN * TT];
            const float* wp = w3t + (ci * 8 + kh) * 96;
#pragma unroll
            for (int oc = 0; oc < 96; oc++) g[oc] = fmaf(v, wp[oc], g[oc]);
        }
    }

    float* gp = g2 + (size_t)b * 96 * NPTS + (size_t)ho * TT + t;
#pragma unroll
    for (int oc = 0; oc < 96; oc++) gp[(size_t)oc * NPTS] = gelu_tanh(g[oc]);
}

// ---------------- layer 2 rewrite (1x1 -> 192) + GLU ----------------
__global__ __launch_bounds__(256) void rw2b_kernel(
    const float* __restrict__ g2, const float* __restrict__ w4t,
    const float* __restrict__ b4, float* __restrict__ outv)
{
    int i = blockIdx.x * 256 + threadIdx.x;   // 0 .. 262143
    int b = i >> 15, p = i & 32767;
    const float* gp = g2 + (size_t)b * 96 * NPTS + p;
    float* op = outv + (size_t)b * 96 * NPTS + p;

    for (int half = 0; half < 2; half++) {
        float za[48], zb[48];
#pragma unroll
        for (int j = 0; j < 48; j++) {
            za[j] = b4[half * 48 + j];
            zb[j] = b4[96 + half * 48 + j];
        }
        for (int c = 0; c < 96; c++) {
            float v = gp[(size_t)c * NPTS];
            const float* wp = w4t + c * 192;
#pragma unroll
            for (int j = 0; j < 48; j++) {
                za[j] = fmaf(v, wp[half * 48 + j], za[j]);
                zb[j] = fmaf(v, wp[96 + half * 48 + j], zb[j]);
            }
        }
#pragma unroll
        for (int j = 0; j < 48; j++) {
            float o = za[j] / (1.f + expf(-zb[j]));
            op[(size_t)(half * 48 + j) * NPTS] = o;
        }
    }
}

// ---------------- VQ: distances, argmin, gather ----------------
__global__ __launch_bounds__(256) void vq_kernel(
    const float* __restrict__ bq, const float* __restrict__ cb,
    const float* __restrict__ cnorm,
    float* __restrict__ latent, float* __restrict__ idxf)
{
    int n = blockIdx.x * 256 + threadIdx.x;   // 0 .. 262143
    int b = n >> 15, p = n & 32767;
    const float* fp = bq + (size_t)b * 96 * NPTS + p;

    float f[96];
#pragma unroll
    for (int c = 0; c < 96; c++) f[c] = fp[(size_t)c * NPTS];

    float best = 3.402823466e+38f, best2 = 3.402823466e+38f;
    int bi = 0, bi2 = 0;
    for (int k = 0; k < 1024; k++) {
        const float* cp = cb + (size_t)k * 96;
        float a0 = 0.f, a1 = 0.f, a2 = 0.f, a3 = 0.f;
#pragma unroll
        for (int d = 0; d < 96; d += 4) {
            a0 = fmaf(f[d],     cp[d],     a0);
            a1 = fmaf(f[d + 1], cp[d + 1], a1);
            a2 = fmaf(f[d + 2], cp[d + 2], a2);
            a3 = fmaf(f[d + 3], cp[d + 3], a3);
        }
        float s = cnorm[k] - 2.f * ((a0 + a1) + (a2 + a3));
        if (s < best) {                       // strict < -> first-min tie-break
            best2 = best; bi2 = bi;
            best = s;     bi = k;
        } else if (s < best2) {
            best2 = s;    bi2 = k;
        }
    }

    // near-tie rescue: fp64 rescore so our argmin is effectively exact
    if (best2 - best < 1e-3f * fmaxf(1.0f, fabsf(best))) {
        const float* c1 = cb + (size_t)bi  * 96;
        const float* c2 = cb + (size_t)bi2 * 96;
        double s1 = 0.0, s2 = 0.0;
#pragma unroll
        for (int d = 0; d < 96; d++) {
            double fd = (double)f[d];
            double x1 = (double)c1[d], x2 = (double)c2[d];
            s1 += x1 * (x1 - 2.0 * fd);
            s2 += x2 * (x2 - 2.0 * fd);
        }
        if (s2 < s1 || (s2 == s1 && bi2 < bi)) bi = bi2;
    }

    idxf[n] = (float)bi;
    const float* cbest = cb + (size_t)bi * 96;
    float* lp = latent + (size_t)b * 96 * NPTS + p;
#pragma unroll
    for (int c = 0; c < 96; c++) lp[(size_t)c * NPTS] = cbest[c];
}

extern "C" void kernel_launch(void* const* d_in, const int* in_sizes, int n_in,
                              void* d_out, int out_size, void* d_ws, size_t ws_size,
                              hipStream_t stream) {
    const float* x  = (const float*)d_in[0];
    const float* w1 = (const float*)d_in[1];
    const float* b1 = (const float*)d_in[2];
    const float* w2 = (const float*)d_in[3];
    const float* b2 = (const float*)d_in[4];
    const float* w3 = (const float*)d_in[5];
    const float* b3 = (const float*)d_in[6];
    const float* w4 = (const float*)d_in[7];
    const float* b4 = (const float*)d_in[8];
    const float* cb = (const float*)d_in[9];

    float* ws    = (float*)d_ws;
    float* y1    = ws;                       // 50331648 floats (201 MB)
    float* w1t   = ws + 50331648;            // 768
    float* w2t   = w1t + 768;                // 4608
    float* w3t   = w2t + 4608;               // 36864
    float* w4t   = w3t + 36864;              // 18432
    float* cnorm = w4t + 18432;              // 1024

    float* out    = (float*)d_out;
    float* latent = out;
    float* idxf   = out + LAT_ELEMS;
    float* bq     = out + LAT_ELEMS + IDX_ELEMS;
    float* g2     = latent;   // latent region is dead until vq_kernel; reuse as conv2 scratch

    prep_kernel<<<241, 256, 0, stream>>>(w1, w2, w3, w4, cb, w1t, w2t, w3t, w4t, cnorm);
    henc1_kernel<<<8 * 512, 256, 0, stream>>>(x, w1t, b1, w2t, b2, y1);
    conv2a_kernel<<<8 * 128, 256, 0, stream>>>(y1, w3t, b3, g2);
    rw2b_kernel<<<1024, 256, 0, stream>>>(g2, w4t, b4, bq);
    vq_kernel<<<1024, 256, 0, stream>>>(bq, cb, cnorm, latent, idxf);
}

// Round 2
// 2120.788 us; speedup vs baseline: 1.6732x; 1.6732x over previous
//
#include <hip/hip_runtime.h>
#include <math.h>

// Shapes:
// x:  [8, 2, 2048, 256]
// L1: conv k(8,1) s(4,1) p(2,0): -> [8,48,512,256]; gelu; 1x1 ->96; GLU -> [8,48,512,256]  (y1, ws)
// L2: conv -> [8,96,128,256]; gelu (g2, staged in d_out latent region); 1x1 ->192; GLU -> beforvq (d_out)
// VQ: argmin over 1024 codes of ||f - c||^2, latent = codebook[idx]
//
// d_out layout (fp32): latent [25165824] | indices-as-float [262144] | beforvq [25165824]

#define H1IN 2048
#define H1OUT 512
#define H2IN 512
#define H2OUT 128
#define TT 256
#define NPTS 32768           // 128*256 per batch
#define LAT_ELEMS 25165824   // 8*96*128*256
#define IDX_ELEMS 262144

// ---------------- prep: transpose weights, codebook norms ----------------
__global__ __launch_bounds__(256) void prep_kernel(
    const float* __restrict__ w1, const float* __restrict__ w2,
    const float* __restrict__ w3, const float* __restrict__ w4,
    const float* __restrict__ cb,
    float* __restrict__ w1t, float* __restrict__ w2t,
    float* __restrict__ w3t, float* __restrict__ w4t,
    float* __restrict__ cnorm)
{
    int i = blockIdx.x * 256 + threadIdx.x;
    if (i < 768) {                       // w1t[(ci*8+kh)*48+oc] = w1[(oc*2+ci)*8+kh]
        int oc = i % 48; int r = i / 48;
        w1t[i] = w1[(oc * 2 + (r >> 3)) * 8 + (r & 7)];
    } else if (i < 5376) {               // w2t[c*96+oc] = w2[oc*48+c]
        int j = i - 768;
        int oc = j % 96, c = j / 96;
        w2t[j] = w2[oc * 48 + c];
    } else if (i < 42240) {              // w3t[(ci*8+kh)*96+oc] = w3[(oc*48+ci)*8+kh]
        int j = i - 5376;
        int oc = j % 96; int r = j / 96;
        w3t[j] = w3[(oc * 48 + (r >> 3)) * 8 + (r & 7)];
    } else if (i < 60672) {              // w4t[c*192+oc] = w4[oc*96+c]
        int j = i - 42240;
        int oc = j % 192, c = j / 192;
        w4t[j] = w4[oc * 96 + c];
    } else if (i < 61696) {              // cnorm[k] = sum_d cb[k][d]^2 (fp64 accumulate)
        int k = i - 60672;
        const float* cp = cb + (size_t)k * 96;
        double s = 0.0;
        for (int d = 0; d < 96; d++) s += (double)cp[d] * (double)cp[d];
        cnorm[k] = (float)s;
    }
}

__device__ __forceinline__ float gelu_tanh(float v) {
    float u = 0.7978845608028654f * (v + 0.044715f * v * v * v);
    return 0.5f * v * (1.f + tanhf(u));
}

// ---------------- layer 1 fused: conv + gelu + 1x1 + GLU ----------------
// launch_bounds(256,2): budget ~256 VGPR -> g[48]+z[96] stay in registers (R1: default
// heuristic capped at ~68 VGPR and spilled the accumulator arrays to scratch).
__global__ __launch_bounds__(256, 2) void henc1_kernel(
    const float* __restrict__ x, const float* __restrict__ w1t,
    const float* __restrict__ b1, const float* __restrict__ w2t,
    const float* __restrict__ b2, float* __restrict__ y1)
{
    __shared__ float gs[48 * 256];
    int bh = blockIdx.x;           // b*512 + ho
    int ho = bh & 511, b = bh >> 9;
    int t = threadIdx.x;

    float g[48];
#pragma unroll
    for (int oc = 0; oc < 48; oc++) g[oc] = b1[oc];

    const float* xb = x + (size_t)b * 2 * H1IN * TT;
    int hbase = ho * 4 - 2;
    for (int ci = 0; ci < 2; ci++) {
        for (int kh = 0; kh < 8; kh++) {
            int hi = hbase + kh;
            float v = (hi >= 0 && hi < H1IN) ? xb[((size_t)ci * H1IN + hi) * TT + t] : 0.f;
            const float* wp = w1t + (ci * 8 + kh) * 48;
#pragma unroll
            for (int oc = 0; oc < 48; oc++) g[oc] = fmaf(v, wp[oc], g[oc]);
        }
    }
#pragma unroll
    for (int oc = 0; oc < 48; oc++) gs[oc * 256 + t] = gelu_tanh(g[oc]);

    float z[96];
#pragma unroll
    for (int oc = 0; oc < 96; oc++) z[oc] = b2[oc];
    for (int c = 0; c < 48; c++) {
        float v = gs[c * 256 + t];
        const float* wp = w2t + c * 96;
#pragma unroll
        for (int oc = 0; oc < 96; oc++) z[oc] = fmaf(v, wp[oc], z[oc]);
    }

    float* yb = y1 + (size_t)b * 48 * H1OUT * TT + (size_t)ho * TT + t;
#pragma unroll
    for (int co = 0; co < 48; co++) {
        float o = z[co] / (1.f + expf(-z[co + 48]));   // a * sigmoid(b)
        yb[(size_t)co * H1OUT * TT] = o;
    }
}

// ---------------- layer 2 conv + gelu ----------------
__global__ __launch_bounds__(256, 2) void conv2a_kernel(
    const float* __restrict__ y1, const float* __restrict__ w3t,
    const float* __restrict__ b3, float* __restrict__ g2)
{
    int bh = blockIdx.x;           // b*128 + ho
    int ho = bh & 127, b = bh >> 7;
    int t = threadIdx.x;

    float g[96];
#pragma unroll
    for (int oc = 0; oc < 96; oc++) g[oc] = b3[oc];

    const float* xb = y1 + (size_t)b * 48 * H2IN * TT;
    int hbase = ho * 4 - 2;
    for (int kh = 0; kh < 8; kh++) {
        int hi = hbase + kh;
        if (hi < 0 || hi >= H2IN) continue;       // wave-uniform branch
        const float* xr = xb + (size_t)hi * TT + t;
        for (int ci = 0; ci < 48; ci++) {
            float v = xr[(size_t)ci * H2IN * TT];
            const float* wp = w3t + (ci * 8 + kh) * 96;
#pragma unroll
            for (int oc = 0; oc < 96; oc++) g[oc] = fmaf(v, wp[oc], g[oc]);
        }
    }

    float* gp = g2 + (size_t)b * 96 * NPTS + (size_t)ho * TT + t;
#pragma unroll
    for (int oc = 0; oc < 96; oc++) gp[(size_t)oc * NPTS] = gelu_tanh(g[oc]);
}

// ---------------- layer 2 rewrite (1x1 -> 192) + GLU ----------------
__global__ __launch_bounds__(256, 2) void rw2b_kernel(
    const float* __restrict__ g2, const float* __restrict__ w4t,
    const float* __restrict__ b4, float* __restrict__ outv)
{
    int i = blockIdx.x * 256 + threadIdx.x;   // 0 .. 262143
    int b = i >> 15, p = i & 32767;
    const float* gp = g2 + (size_t)b * 96 * NPTS + p;
    float* op = outv + (size_t)b * 96 * NPTS + p;

    for (int half = 0; half < 2; half++) {
        float za[48], zb[48];
#pragma unroll
        for (int j = 0; j < 48; j++) {
            za[j] = b4[half * 48 + j];
            zb[j] = b4[96 + half * 48 + j];
        }
        for (int c = 0; c < 96; c++) {
            float v = gp[(size_t)c * NPTS];
            const float* wp = w4t + c * 192;
#pragma unroll
            for (int j = 0; j < 48; j++) {
                za[j] = fmaf(v, wp[half * 48 + j], za[j]);
                zb[j] = fmaf(v, wp[96 + half * 48 + j], zb[j]);
            }
        }
#pragma unroll
        for (int j = 0; j < 48; j++) {
            float o = za[j] / (1.f + expf(-zb[j]));
            op[(size_t)(half * 48 + j) * NPTS] = o;
        }
    }
}

// ---------------- VQ: distances, argmin, gather ----------------
// launch_bounds(256,3): VGPR budget ~170 so f[96] lives in registers (R1 spilled at 68).
// The cold fp64 rescue path RELOADS f from global so f's live range ends at the k-loop.
__global__ __launch_bounds__(256, 3) void vq_kernel(
    const float* __restrict__ bq, const float* __restrict__ cb,
    const float* __restrict__ cnorm,
    float* __restrict__ latent, float* __restrict__ idxf)
{
    int n = blockIdx.x * 256 + threadIdx.x;   // 0 .. 262143
    int b = n >> 15, p = n & 32767;
    const float* fp = bq + (size_t)b * 96 * NPTS + p;

    float f[96];
#pragma unroll
    for (int c = 0; c < 96; c++) f[c] = fp[(size_t)c * NPTS];

    float best = 3.402823466e+38f, best2 = 3.402823466e+38f;
    int bi = 0, bi2 = 0;
    for (int k = 0; k < 1024; k++) {
        const float* cp = cb + (size_t)k * 96;
        float a0 = 0.f, a1 = 0.f, a2 = 0.f, a3 = 0.f;
#pragma unroll
        for (int d = 0; d < 96; d += 4) {
            a0 = fmaf(f[d],     cp[d],     a0);
            a1 = fmaf(f[d + 1], cp[d + 1], a1);
            a2 = fmaf(f[d + 2], cp[d + 2], a2);
            a3 = fmaf(f[d + 3], cp[d + 3], a3);
        }
        float s = cnorm[k] - 2.f * ((a0 + a1) + (a2 + a3));
        if (s < best) {                       // strict < -> first-min tie-break
            best2 = best; bi2 = bi;
            best = s;     bi = k;
        } else if (s < best2) {
            best2 = s;    bi2 = k;
        }
    }

    // near-tie rescue: fp64 rescore (cold; reloads f so the hot loop's f stays reg-only)
    if (best2 - best < 1e-3f * fmaxf(1.0f, fabsf(best))) {
        const float* c1 = cb + (size_t)bi  * 96;
        const float* c2 = cb + (size_t)bi2 * 96;
        double s1 = 0.0, s2 = 0.0;
        for (int d = 0; d < 96; d++) {
            double fd = (double)fp[(size_t)d * NPTS];
            double x1 = (double)c1[d], x2 = (double)c2[d];
            s1 += x1 * (x1 - 2.0 * fd);
            s2 += x2 * (x2 - 2.0 * fd);
        }
        if (s2 < s1 || (s2 == s1 && bi2 < bi)) bi = bi2;
    }

    idxf[n] = (float)bi;
    const float* cbest = cb + (size_t)bi * 96;
    float* lp = latent + (size_t)b * 96 * NPTS + p;
#pragma unroll
    for (int c = 0; c < 96; c++) lp[(size_t)c * NPTS] = cbest[c];
}

extern "C" void kernel_launch(void* const* d_in, const int* in_sizes, int n_in,
                              void* d_out, int out_size, void* d_ws, size_t ws_size,
                              hipStream_t stream) {
    const float* x  = (const float*)d_in[0];
    const float* w1 = (const float*)d_in[1];
    const float* b1 = (const float*)d_in[2];
    const float* w2 = (const float*)d_in[3];
    const float* b2 = (const float*)d_in[4];
    const float* w3 = (const float*)d_in[5];
    const float* b3 = (const float*)d_in[6];
    const float* w4 = (const float*)d_in[7];
    const float* b4 = (const float*)d_in[8];
    const float* cb = (const float*)d_in[9];

    float* ws    = (float*)d_ws;
    float* y1    = ws;                       // 50331648 floats (201 MB)
    float* w1t   = ws + 50331648;            // 768
    float* w2t   = w1t + 768;                // 4608
    float* w3t   = w2t + 4608;               // 36864
    float* w4t   = w3t + 36864;              // 18432
    float* cnorm = w4t + 18432;              // 1024

    float* out    = (float*)d_out;
    float* latent = out;
    float* idxf   = out + LAT_ELEMS;
    float* bq     = out + LAT_ELEMS + IDX_ELEMS;
    float* g2     = latent;   // latent region is dead until vq_kernel; reuse as conv2 scratch

    prep_kernel<<<241, 256, 0, stream>>>(w1, w2, w3, w4, cb, w1t, w2t, w3t, w4t, cnorm);
    henc1_kernel<<<8 * 512, 256, 0, stream>>>(x, w1t, b1, w2t, b2, y1);
    conv2a_kernel<<<8 * 128, 256, 0, stream>>>(y1, w3t, b3, g2);
    rw2b_kernel<<<1024, 256, 0, stream>>>(g2, w4t, b4, bq);
    vq_kernel<<<1024, 256, 0, stream>>>(bq, cb, cnorm, latent, idxf);
}